// Round 1
// baseline (3240.610 us; speedup 1.0000x reference)
//
#include <hip/hip_runtime.h>

// GlobalNet conv-GRU on MI355X.
// Design: per timestep t: two bf16 MFMA GEMMs (x-part K=320, h-part K=800,
// N padded 450->512) -> Sx/Sh fp32 score buffers -> pointwise gate update
// (h kept fp32, bf16 shadow for MFMA). Head matmuls in fp32 at the end.

#define Bn   16
#define Tn   64
#define Ln   512
#define Cn   64
#define Hn   150
#define G3   450
#define NPAD 512
#define HP   160   // padded hidden per tap (mult of 32)
#define KPH  800   // 5*HP
#define KPX  320   // 5*Cn
#define MT   128
#define NT   64
#define WIN  132   // MT+4 window rows
#define ASTH 168   // LDS row stride (h window), mult of 8, decent bank spread
#define ASTX 72    // LDS row stride (x window)
#define Mtot 8192  // Bn*Ln

typedef __bf16 bf16x8 __attribute__((ext_vector_type(8)));
typedef float  f32x4  __attribute__((ext_vector_type(4)));
typedef short  s16x4  __attribute__((ext_vector_type(4)));

__device__ inline short f2bf(float f) {
  unsigned u = __builtin_bit_cast(unsigned, f);
  u += 0x7fffu + ((u >> 16) & 1u);   // RNE (inputs finite)
  return (short)(u >> 16);
}

// Pack weights to bf16, n-major [n][k], k-contiguous so B fragments are 16B loads.
// Bh[n][kk*160+j] = kh[kk][j][n] (j<150, n<450 else 0); Bx[n][kk*64+c] = ki[kk][c][n].
__global__ __launch_bounds__(256) void pack_weights(const float* __restrict__ ki,
                                                    const float* __restrict__ kh,
                                                    short* __restrict__ Bx,
                                                    short* __restrict__ Bh) {
  int idx = blockIdx.x * 256 + threadIdx.x;
  if (idx < NPAD * KPH) {
    int n = idx / KPH, k = idx - n * KPH;
    int kk = k / HP, j = k - kk * HP;
    float v = (n < G3 && j < Hn) ? kh[(kk * Hn + j) * G3 + n] : 0.f;
    Bh[idx] = f2bf(v);
  } else {
    int r = idx - NPAD * KPH;
    if (r < NPAD * KPX) {
      int n = r / KPX, k = r - n * KPX;
      int kk = k / Cn, c = k - kk * Cn;
      float v = (n < G3) ? ki[(kk * Cn + c) * G3 + n] : 0.f;
      Bx[r] = f2bf(v);
    }
  }
}

// KIND 0: h-conv GEMM (A = h window from bf16 h buffer, K=800)
// KIND 1: x-conv GEMM (A = xs window, fp32->bf16 on the fly, K=320)
// Block tile 128M x 64N, 4 waves (2M x 2N), wave tile 64M x 32N.
// A window staged once to LDS (covers full K); no barrier in K-loop.
// B fragments loaded straight from global (L2), register double-buffered.
template <int KIND>
__launch_bounds__(256, 3)
__global__ void gemm_step(const short* __restrict__ hbf, const float* __restrict__ xs,
                          const short* __restrict__ Bw, float* __restrict__ S, int t) {
  constexpr int KC  = (KIND == 0) ? 25 : 10;     // k-chunks of 32
  constexpr int SEG = (KIND == 0) ? 5 : 2;       // k-chunks per tap
  constexpr int AST = (KIND == 0) ? ASTH : ASTX;
  constexpr int KP  = (KIND == 0) ? KPH : KPX;
  __shared__ short aw[WIN * AST];

  const int tid = threadIdx.x;
  const int bb  = blockIdx.y >> 2;          // batch
  const int l0  = (blockIdx.y & 3) * MT;    // first output position

  if (KIND == 0) {
    for (int i = tid; i < WIN * 42; i += 256) {   // 42 s16x4 units per row
      int r = i / 42, c4 = (i - r * 42) * 4;
      int l = l0 - 2 + r;
      s16x4 v = {0, 0, 0, 0};
      if (c4 < HP && l >= 0 && l < Ln)
        v = *(const s16x4*)&hbf[(bb * Ln + l) * HP + c4];
      *(s16x4*)&aw[r * AST + c4] = v;
    }
  } else {
    for (int i = tid; i < WIN * 18; i += 256) {   // 18 s16x4 units per row (64 data + 8 pad)
      int r = i / 18, c4 = (i - r * 18) * 4;
      int l = l0 - 2 + r;
      s16x4 v = {0, 0, 0, 0};
      if (c4 < Cn && l >= 0 && l < Ln) {
        f32x4 f = *(const f32x4*)&xs[(((size_t)bb * Tn + t) * Ln + l) * Cn + c4];
        v[0] = f2bf(f[0]); v[1] = f2bf(f[1]); v[2] = f2bf(f[2]); v[3] = f2bf(f[3]);
      }
      *(s16x4*)&aw[r * AST + c4] = v;
    }
  }
  __syncthreads();

  const int lane = tid & 63, wave = tid >> 6;
  const int quad = lane >> 4, l16 = lane & 15;
  const int wm = wave & 1, wn = wave >> 1;

  const short* Bbase = Bw + (size_t)(blockIdx.x * NT + wn * 32 + l16) * KP + quad * 8;
  const int arow0 = (wm * 64 + l16) * AST + quad * 8;

  f32x4 acc[4][2] = {};

  bf16x8 a_c[4], b_c[2];
  {
    const short* ar = &aw[arow0];            // kc=0: kk=0, jj=0
    a_c[0] = *(const bf16x8*)(ar);
    a_c[1] = *(const bf16x8*)(ar + 16 * AST);
    a_c[2] = *(const bf16x8*)(ar + 32 * AST);
    a_c[3] = *(const bf16x8*)(ar + 48 * AST);
    b_c[0] = *(const bf16x8*)(Bbase);
    b_c[1] = *(const bf16x8*)(Bbase + 16 * KP);
  }

  for (int kc = 0; kc < KC; ++kc) {
    int kcn = (kc + 1 < KC) ? (kc + 1) : kc;     // clamped prefetch (branch-free)
    int kk  = kcn / SEG;
    int jj  = (kcn - kk * SEG) * 32;
    const short* ar = &aw[arow0 + kk * AST + jj];
    bf16x8 a_n[4], b_n[2];
    a_n[0] = *(const bf16x8*)(ar);
    a_n[1] = *(const bf16x8*)(ar + 16 * AST);
    a_n[2] = *(const bf16x8*)(ar + 32 * AST);
    a_n[3] = *(const bf16x8*)(ar + 48 * AST);
    b_n[0] = *(const bf16x8*)(Bbase + kcn * 32);
    b_n[1] = *(const bf16x8*)(Bbase + 16 * KP + kcn * 32);
#pragma unroll
    for (int mi = 0; mi < 4; ++mi)
#pragma unroll
      for (int ni = 0; ni < 2; ++ni)
        acc[mi][ni] = __builtin_amdgcn_mfma_f32_16x16x32_bf16(a_c[mi], b_c[ni], acc[mi][ni], 0, 0, 0);
#pragma unroll
    for (int mi = 0; mi < 4; ++mi) a_c[mi] = a_n[mi];
    b_c[0] = b_n[0]; b_c[1] = b_n[1];
  }

  // C/D layout: col = lane&15, row = quad*4 + reg  (m89/m91-verified)
  const int mb = blockIdx.y * MT + wm * 64 + quad * 4;
  const int nb = blockIdx.x * NT + wn * 32 + l16;
#pragma unroll
  for (int mi = 0; mi < 4; ++mi)
#pragma unroll
    for (int ni = 0; ni < 2; ++ni)
#pragma unroll
      for (int r = 0; r < 4; ++r)
        S[(size_t)(mb + mi * 16 + r) * NPAD + nb + ni * 16] = acc[mi][ni][r];
}

// Pointwise GRU gate update. h carried in fp32; bf16 shadow written for next GEMM.
__global__ __launch_bounds__(256) void update_h(const float* __restrict__ Sh,
                                                const float* __restrict__ Sx,
                                                float* __restrict__ hf,
                                                short* __restrict__ hb) {
  int idx = blockIdx.x * 256 + threadIdx.x;
  if (idx >= Mtot * Hn) return;
  int m = idx / Hn, j = idx - m * Hn;
  const float* sh = Sh + (size_t)m * NPAD;
  const float* sx = Sx + (size_t)m * NPAD;
  float r = 1.f / (1.f + __expf(-(sx[j] + sh[j])));
  float z = 1.f / (1.f + __expf(-(sx[Hn + j] + sh[Hn + j])));
  float xg = sx[2 * Hn + j] + r * sh[2 * Hn + j];
  xg = fminf(fmaxf(xg, -15.f), 15.f);
  float e = __expf(2.f * xg);
  float n = (e - 1.f) / (e + 1.f);
  float h = hf[idx];
  float hn = (1.f - z) * n + z * h;
  hf[idx] = hn;
  hb[m * HP + j] = f2bf(hn);
}

// Head: out = silu(h @ W1 + b1) @ W2 + b2, fp32. 64 rows per block.
__global__ __launch_bounds__(256) void head_kernel(const float* __restrict__ hf,
                                                   const float* __restrict__ W1,
                                                   const float* __restrict__ b1,
                                                   const float* __restrict__ W2,
                                                   const float* __restrict__ b2,
                                                   float* __restrict__ out) {
  __shared__ float hl[64][151];  // +1 pad: odd stride -> conflict-free
  __shared__ float dl[64][153];
  const int tid = threadIdx.x;
  const int mb = blockIdx.x * 64;
  for (int i = tid; i < 64 * Hn; i += 256) {
    int r = i / Hn, c = i - r * Hn;
    hl[r][c] = hf[(size_t)(mb + r) * Hn + c];
  }
  __syncthreads();
  const int lane = tid & 63, w = tid >> 6;
  for (int jj = w; jj < Hn; jj += 4) {
    float acc = b1[jj];
    for (int i = 0; i < Hn; ++i) acc += hl[lane][i] * W1[i * Hn + jj];
    dl[lane][jj] = acc / (1.f + __expf(-acc));   // silu
  }
  __syncthreads();
  for (int jj = w; jj < 24; jj += 4) {
    float acc = b2[jj];
    for (int i = 0; i < Hn; ++i) acc += dl[lane][i] * W2[i * 24 + jj];
    out[(size_t)(mb + lane) * 24 + jj] = acc;
  }
}

extern "C" void kernel_launch(void* const* d_in, const int* in_sizes, int n_in,
                              void* d_out, int out_size, void* d_ws, size_t ws_size,
                              hipStream_t stream) {
  const float* xs = (const float*)d_in[0];
  const float* ki = (const float*)d_in[1];
  const float* kh = (const float*)d_in[2];
  const float* W1 = (const float*)d_in[3];
  const float* b1 = (const float*)d_in[4];
  const float* W2 = (const float*)d_in[5];
  const float* b2 = (const float*)d_in[6];
  float* out = (float*)d_out;

  // Workspace layout (~42.3 MB total)
  char* p = (char*)d_ws;
  float* Sh = (float*)p; p += (size_t)Mtot * NPAD * 4;
  float* Sx = (float*)p; p += (size_t)Mtot * NPAD * 4;
  float* hf = (float*)p; p += (size_t)Mtot * Hn * 4;
  short* hb = (short*)p; p += (size_t)Mtot * HP * 2;
  short* Bh = (short*)p; p += (size_t)NPAD * KPH * 2;
  short* Bx = (short*)p; p += (size_t)NPAD * KPX * 2;

  hipMemsetAsync(hf, 0, (size_t)Mtot * Hn * 4, stream);
  hipMemsetAsync(hb, 0, (size_t)Mtot * HP * 2, stream);  // keeps j-pad cols zero forever
  pack_weights<<<(NPAD * KPH + NPAD * KPX) / 256, 256, 0, stream>>>(ki, kh, Bx, Bh);

  for (int t = 0; t < Tn; ++t) {
    gemm_step<0><<<dim3(8, 64), 256, 0, stream>>>(hb, nullptr, Bh, Sh, t);
    gemm_step<1><<<dim3(8, 64), 256, 0, stream>>>(nullptr, xs, Bx, Sx, t);
    update_h<<<(Mtot * Hn + 255) / 256, 256, 0, stream>>>(Sh, Sx, hf, hb);
  }
  head_kernel<<<Mtot / 64, 256, 0, stream>>>(hf, W1, b1, W2, b2, out);
}

// Round 2
// 2852.336 us; speedup vs baseline: 1.1361x; 1.1361x over previous
//
#include <hip/hip_runtime.h>

// GlobalNet conv-GRU on MI355X — round 2.
// x-conv hoisted out of the scan (batched GEMM -> bf16 Sx, Tc-chunked by ws_size).
// Both GEMMs: 128x128 block, 512 thr (8 waves), wave-tile 32Mx64N (4x n-reuse
// per LDS A-read -> MFMA-bound). h-GEMM grid 256 = 1 block/CU exact fit.
// Head: one-thread-per-output fp32 kernels (old head was latency-bound 180 us).

#define Bn   16
#define Tn   64
#define Ln   512
#define Cn   64
#define Hn   150
#define G3   450
#define NS   512    // S width: segments r|z|n at 160 offsets + 32 dead cols
#define SW   160    // segment width
#define HP   160    // padded hidden
#define KH   800    // 5*HP
#define KX   320    // 5*Cn
#define Mtot 8192   // Bn*Ln

typedef __bf16 bf16x8 __attribute__((ext_vector_type(8)));
typedef float  f32x4  __attribute__((ext_vector_type(4)));
typedef short  s16x4  __attribute__((ext_vector_type(4)));

__device__ inline short f2bf(float f) {
  unsigned u = __builtin_bit_cast(unsigned, f);
  u += 0x7fffu + ((u >> 16) & 1u);   // RNE (finite inputs)
  return (short)(u >> 16);
}
__device__ inline float bf2f(short s) {
  unsigned u = ((unsigned)(unsigned short)s) << 16;
  return __builtin_bit_cast(float, u);
}

// B matrices packed n-major, k-contiguous. n = seg*160 + jl, seg in {r,z,n}:
// orig output col = seg*150 + jl (jl<150), zero-padded elsewhere (incl n>=480).
__global__ __launch_bounds__(256) void pack_weights(const float* __restrict__ ki,
                                                    const float* __restrict__ kh,
                                                    short* __restrict__ Bx,
                                                    short* __restrict__ Bh) {
  int idx = blockIdx.x * 256 + threadIdx.x;
  if (idx < NS * KH) {
    int n = idx / KH, k = idx - n * KH;
    int kk = k / HP, jj = k - kk * HP;
    int seg = n / SW, jl = n - seg * SW;
    float v = 0.f;
    if (seg < 3 && jl < Hn && jj < Hn) v = kh[(kk * Hn + jj) * G3 + seg * Hn + jl];
    Bh[idx] = f2bf(v);
  } else {
    int r = idx - NS * KH;
    if (r < NS * KX) {
      int n = r / KX, k = r - n * KX;
      int kk = k / Cn, c = k - kk * Cn;
      int seg = n / SW, jl = n - seg * SW;
      float v = 0.f;
      if (seg < 3 && jl < Hn) v = ki[(kk * Cn + c) * G3 + seg * Hn + jl];
      Bx[r] = f2bf(v);
    }
  }
}

// Batched x-conv GEMM: M = Bn*Tc*Ln rows, K=320, N=512 -> Sx bf16.
// Block 128Mx128N, 8 waves as (wm 0..3, wn 0..1), wave tile 32Mx64N.
__global__ __launch_bounds__(512) void gemm_x(const float* __restrict__ xs,
                                              const short* __restrict__ Bx,
                                              short* __restrict__ Sx,
                                              int tc0, int Tc) {
  __shared__ short aw[132 * 72];
  const int tid = threadIdx.x;
  const int lch = blockIdx.y & 3;
  const int bt  = blockIdx.y >> 2;
  const int b   = bt / Tc, trel = bt - b * Tc;
  const int t   = tc0 + trel;
  const int l0  = lch * 128;

  for (int i = tid; i < 132 * 16; i += 512) {
    int r = i >> 4, c4 = (i & 15) * 4;
    int l = l0 - 2 + r;
    s16x4 v = {0, 0, 0, 0};
    if (l >= 0 && l < Ln) {
      f32x4 f = *(const f32x4*)&xs[(((size_t)b * Tn + t) * Ln + l) * Cn + c4];
      v[0] = f2bf(f[0]); v[1] = f2bf(f[1]); v[2] = f2bf(f[2]); v[3] = f2bf(f[3]);
    }
    *(s16x4*)&aw[r * 72 + c4] = v;
  }
  __syncthreads();

  const int lane = tid & 63, wave = tid >> 6;
  const int quad = lane >> 4, l16 = lane & 15;
  const int wm = wave & 3, wn = wave >> 2;

  const short* Bp[4];
#pragma unroll
  for (int nf = 0; nf < 4; ++nf)
    Bp[nf] = Bx + (size_t)(blockIdx.x * 128 + wn * 64 + nf * 16 + l16) * KX + quad * 8;
  const int ar0 = (wm * 32 + l16) * 72 + quad * 8;

  f32x4 acc[2][4] = {};
  bf16x8 a_c[2], b_c[4];
  a_c[0] = *(const bf16x8*)&aw[ar0];
  a_c[1] = *(const bf16x8*)&aw[ar0 + 16 * 72];
#pragma unroll
  for (int nf = 0; nf < 4; ++nf) b_c[nf] = *(const bf16x8*)(Bp[nf]);

  int kk = 0, jj = 0;
  for (int kc = 0; kc < 10; ++kc) {
    bool last = (kc == 9);
    int jj2 = jj + 32, kk2 = kk;
    if (jj2 == 64) { jj2 = 0; kk2 = kk + 1; }
    if (last) { jj2 = jj; kk2 = kk; }
    int kb = last ? kc : kc + 1;
    const short* ar = &aw[ar0 + kk2 * 72 + jj2];
    bf16x8 a_n[2], b_n[4];
    a_n[0] = *(const bf16x8*)(ar);
    a_n[1] = *(const bf16x8*)(ar + 16 * 72);
#pragma unroll
    for (int nf = 0; nf < 4; ++nf) b_n[nf] = *(const bf16x8*)(Bp[nf] + kb * 32);
#pragma unroll
    for (int mi = 0; mi < 2; ++mi)
#pragma unroll
      for (int nf = 0; nf < 4; ++nf)
        acc[mi][nf] = __builtin_amdgcn_mfma_f32_16x16x32_bf16(a_c[mi], b_c[nf], acc[mi][nf], 0, 0, 0);
    a_c[0] = a_n[0]; a_c[1] = a_n[1];
#pragma unroll
    for (int nf = 0; nf < 4; ++nf) b_c[nf] = b_n[nf];
    kk = kk2; jj = jj2;
  }

  const size_t mrow = (size_t)(b * Tc + trel) * Ln + l0 + wm * 32 + quad * 4;
  const int n0 = blockIdx.x * 128 + wn * 64 + l16;
#pragma unroll
  for (int mi = 0; mi < 2; ++mi)
#pragma unroll
    for (int nf = 0; nf < 4; ++nf)
#pragma unroll
      for (int r = 0; r < 4; ++r)
        Sx[(mrow + mi * 16 + r) * NS + n0 + nf * 16] = f2bf(acc[mi][nf][r]);
}

// Recurrent h-conv GEMM: M=8192, K=800, N=512 -> Sh fp32. Grid (4,64) = 256 blocks.
__global__ __launch_bounds__(512) void gemm_h(const short* __restrict__ hbf,
                                              const short* __restrict__ Bh,
                                              float* __restrict__ Sh) {
  __shared__ short aw[132 * 168];   // 44.4 KB window
  const int tid = threadIdx.x;
  const int bb = blockIdx.y >> 2;
  const int l0 = (blockIdx.y & 3) * 128;

  for (int i = tid; i < 132 * 40; i += 512) {
    int r = i / 40, c4 = (i - r * 40) * 4;
    int l = l0 - 2 + r;
    s16x4 v = {0, 0, 0, 0};
    if (l >= 0 && l < Ln) v = *(const s16x4*)&hbf[((size_t)bb * Ln + l) * HP + c4];
    *(s16x4*)&aw[r * 168 + c4] = v;
  }
  __syncthreads();

  const int lane = tid & 63, wave = tid >> 6;
  const int quad = lane >> 4, l16 = lane & 15;
  const int wm = wave & 3, wn = wave >> 2;

  const short* Bp[4];
#pragma unroll
  for (int nf = 0; nf < 4; ++nf)
    Bp[nf] = Bh + (size_t)(blockIdx.x * 128 + wn * 64 + nf * 16 + l16) * KH + quad * 8;
  const int ar0 = (wm * 32 + l16) * 168 + quad * 8;

  f32x4 acc[2][4] = {};
  bf16x8 a_c[2], b_c[4];
  a_c[0] = *(const bf16x8*)&aw[ar0];
  a_c[1] = *(const bf16x8*)&aw[ar0 + 16 * 168];
#pragma unroll
  for (int nf = 0; nf < 4; ++nf) b_c[nf] = *(const bf16x8*)(Bp[nf]);

  int kk = 0, jj = 0;
  for (int kc = 0; kc < 25; ++kc) {
    bool last = (kc == 24);
    int jj2 = jj + 32, kk2 = kk;
    if (jj2 == 160) { jj2 = 0; kk2 = kk + 1; }
    if (last) { jj2 = jj; kk2 = kk; }
    int kb = last ? kc : kc + 1;
    const short* ar = &aw[ar0 + kk2 * 168 + jj2];
    bf16x8 a_n[2], b_n[4];
    a_n[0] = *(const bf16x8*)(ar);
    a_n[1] = *(const bf16x8*)(ar + 16 * 168);
#pragma unroll
    for (int nf = 0; nf < 4; ++nf) b_n[nf] = *(const bf16x8*)(Bp[nf] + kb * 32);
#pragma unroll
    for (int mi = 0; mi < 2; ++mi)
#pragma unroll
      for (int nf = 0; nf < 4; ++nf)
        acc[mi][nf] = __builtin_amdgcn_mfma_f32_16x16x32_bf16(a_c[mi], b_c[nf], acc[mi][nf], 0, 0, 0);
    a_c[0] = a_n[0]; a_c[1] = a_n[1];
#pragma unroll
    for (int nf = 0; nf < 4; ++nf) b_c[nf] = b_n[nf];
    kk = kk2; jj = jj2;
  }

  const int m0 = blockIdx.y * 128 + wm * 32 + quad * 4;
  const int n0 = blockIdx.x * 128 + wn * 64 + l16;
#pragma unroll
  for (int mi = 0; mi < 2; ++mi)
#pragma unroll
    for (int nf = 0; nf < 4; ++nf)
#pragma unroll
      for (int r = 0; r < 4; ++r)
        Sh[(size_t)(m0 + mi * 16 + r) * NS + n0 + nf * 16] = acc[mi][nf][r];
}

// Pointwise GRU gates. h fp32 carried; bf16 shadow for the next GEMM.
__global__ __launch_bounds__(256) void update_h(const float* __restrict__ Sh,
                                                const short* __restrict__ Sx,
                                                float* __restrict__ hf,
                                                short* __restrict__ hb,
                                                int trel, int Tc) {
  int idx = blockIdx.x * 256 + threadIdx.x;
  if (idx >= Mtot * Hn) return;
  int m = idx / Hn, j = idx - m * Hn;
  int b = m >> 9, l = m & 511;
  const float* sh = Sh + (size_t)m * NS;
  const short* sx = Sx + ((size_t)(b * Tc + trel) * Ln + l) * NS;
  float r = 1.f / (1.f + __expf(-(sh[j] + bf2f(sx[j]))));
  float z = 1.f / (1.f + __expf(-(sh[SW + j] + bf2f(sx[SW + j]))));
  float xg = bf2f(sx[2 * SW + j]) + r * sh[2 * SW + j];
  xg = fminf(fmaxf(xg, -15.f), 15.f);
  float e = __expf(2.f * xg);
  float n = (e - 1.f) / (e + 1.f);
  float hn = (1.f - z) * n + z * hf[idx];
  hf[idx] = hn;
  hb[m * HP + j] = f2bf(hn);
}

// Head: thread-per-output fp32 (coalesced W cols, broadcast h row via L1).
__global__ __launch_bounds__(256) void head1(const float* __restrict__ hf,
                                             const float* __restrict__ W1,
                                             const float* __restrict__ b1,
                                             float* __restrict__ hdn) {
  int idx = blockIdx.x * 256 + threadIdx.x;
  if (idx >= Mtot * Hn) return;
  int m = idx / Hn, j = idx - m * Hn;
  const float* hr = hf + (size_t)m * Hn;
  float acc = b1[j];
#pragma unroll 10
  for (int i = 0; i < Hn; ++i) acc = fmaf(hr[i], W1[i * Hn + j], acc);
  hdn[idx] = acc / (1.f + __expf(-acc));   // silu
}
__global__ __launch_bounds__(256) void head2(const float* __restrict__ hdn,
                                             const float* __restrict__ W2,
                                             const float* __restrict__ b2,
                                             float* __restrict__ out) {
  int idx = blockIdx.x * 256 + threadIdx.x;
  if (idx >= Mtot * 24) return;
  int m = idx / 24, j = idx - m * 24;
  const float* hr = hdn + (size_t)m * Hn;
  float acc = b2[j];
#pragma unroll 10
  for (int i = 0; i < Hn; ++i) acc = fmaf(hr[i], W2[i * 24 + j], acc);
  out[idx] = acc;
}

extern "C" void kernel_launch(void* const* d_in, const int* in_sizes, int n_in,
                              void* d_out, int out_size, void* d_ws, size_t ws_size,
                              hipStream_t stream) {
  const float* xs = (const float*)d_in[0];
  const float* ki = (const float*)d_in[1];
  const float* kh = (const float*)d_in[2];
  const float* W1 = (const float*)d_in[3];
  const float* b1 = (const float*)d_in[4];
  const float* W2 = (const float*)d_in[5];
  const float* b2 = (const float*)d_in[6];
  float* out = (float*)d_out;

  char* p = (char*)d_ws;
  float* Sh = (float*)p; p += (size_t)Mtot * NS * 4;     // 16 MiB (reused as hdn)
  float* hf = (float*)p; p += (size_t)Mtot * Hn * 4;     // 4.7 MiB
  short* hb = (short*)p; p += (size_t)Mtot * HP * 2;     // 2.5 MiB
  short* Bh = (short*)p; p += (size_t)NS * KH * 2;       // 0.8 MiB
  short* Bx = (short*)p; p += (size_t)NS * KX * 2;       // 0.3 MiB
  size_t fixed = (size_t)(p - (char*)d_ws);
  size_t per_t = (size_t)Bn * Ln * NS * 2;               // 8 MiB per timestep
  int Tc = 1;
  for (int c : {64, 32, 16, 8, 4, 2}) {
    if (fixed + (size_t)c * per_t <= ws_size) { Tc = c; break; }
  }
  short* Sx = (short*)p;
  float* hdn = Sh;  // Sh is dead after the scan; reuse for head intermediate

  hipMemsetAsync(hf, 0, (size_t)Mtot * Hn * 4, stream);
  hipMemsetAsync(hb, 0, (size_t)Mtot * HP * 2, stream);  // pad cols stay zero
  pack_weights<<<(NS * KH + NS * KX) / 256, 256, 0, stream>>>(ki, kh, Bx, Bh);

  for (int tc0 = 0; tc0 < Tn; tc0 += Tc) {
    gemm_x<<<dim3(4, Bn * Tc * 4), 512, 0, stream>>>(xs, Bx, Sx, tc0, Tc);
    for (int t = tc0; t < tc0 + Tc; ++t) {
      gemm_h<<<dim3(4, 64), 512, 0, stream>>>(hb, Bh, Sh);
      update_h<<<(Mtot * Hn + 255) / 256, 256, 0, stream>>>(Sh, Sx, hf, hb, t - tc0, Tc);
    }
  }
  head1<<<(Mtot * Hn + 255) / 256, 256, 0, stream>>>(hf, W1, b1, hdn);
  head2<<<(Mtot * 24 + 255) / 256, 256, 0, stream>>>(hdn, W2, b2, out);
}

// Round 3
// 2106.717 us; speedup vs baseline: 1.5382x; 1.3539x over previous
//
#include <hip/hip_runtime.h>

// GlobalNet conv-GRU on MI355X — round 3.
// Key fix vs r2: B matrices repacked wave-fragment-contiguous ([ntile][kc][lane][8])
// so every B-fragment load is one coalesced 1KB wave transaction (r2 scattered 64
// cache lines per load -> MfmaUtil 9.6%). Sh now bf16 (halves S traffic in scan);
// epilogue stores predicated to skip dead cols.

#define Bn   16
#define Tn   64
#define Ln   512
#define Cn   64
#define Hn   150
#define G3   450
#define NS   512    // S width: segments r|z|n at 160 offsets + 32 dead cols
#define SW   160    // segment width
#define HP   160    // padded hidden
#define KCH  25     // k-chunks (32) for h GEMM (K=800)
#define KCX  10     // k-chunks for x GEMM (K=320)
#define Mtot 8192   // Bn*Ln

typedef __bf16 bf16x8 __attribute__((ext_vector_type(8)));
typedef float  f32x4  __attribute__((ext_vector_type(4)));
typedef short  s16x4  __attribute__((ext_vector_type(4)));

__device__ inline short f2bf(float f) {
  unsigned u = __builtin_bit_cast(unsigned, f);
  u += 0x7fffu + ((u >> 16) & 1u);   // RNE (finite inputs)
  return (short)(u >> 16);
}
__device__ inline float bf2f(short s) {
  unsigned u = ((unsigned)(unsigned short)s) << 16;
  return __builtin_bit_cast(float, u);
}

// Packed B layout: [nt (n/16)][kc][lane (quad*16+l16)][j (8)] shorts.
// Fragment element: B[k = kc*32+quad*8+j][n = nt*16+l16].
// n maps (seg = n/160, jl = n%160) -> orig col seg*150+jl (zero pad elsewhere).
// h: k -> tap kk=kc/5, hidden jj=(kc%5)*32+quad*8+j (zero if jj>=150).
// x: k -> tap kk=kc/2, chan  cc=(kc%2)*32+quad*8+j.
__global__ __launch_bounds__(256) void pack_weights(const float* __restrict__ ki,
                                                    const float* __restrict__ kh,
                                                    short* __restrict__ Bx,
                                                    short* __restrict__ Bh) {
  int idx = blockIdx.x * 256 + threadIdx.x;
  if (idx < 32 * KCH * 512) {
    int j = idx & 7, lane = (idx >> 3) & 63;
    int rest = idx >> 9;
    int kc = rest % KCH, nt = rest / KCH;
    int quad = lane >> 4, l16 = lane & 15;
    int n = nt * 16 + l16, seg = n / SW, jl = n - seg * SW;
    int kk = kc / 5, jj = (kc - kk * 5) * 32 + quad * 8 + j;
    float v = (seg < 3 && jl < Hn && jj < Hn) ? kh[(kk * Hn + jj) * G3 + seg * Hn + jl] : 0.f;
    Bh[idx] = f2bf(v);
  } else {
    int r = idx - 32 * KCH * 512;
    if (r < 32 * KCX * 512) {
      int j = r & 7, lane = (r >> 3) & 63;
      int rest = r >> 9;
      int kc = rest % KCX, nt = rest / KCX;
      int quad = lane >> 4, l16 = lane & 15;
      int n = nt * 16 + l16, seg = n / SW, jl = n - seg * SW;
      int kk = kc / 2, cc = (kc - kk * 2) * 32 + quad * 8 + j;
      float v = (seg < 3 && jl < Hn) ? ki[(kk * Cn + cc) * G3 + seg * Hn + jl] : 0.f;
      Bx[r] = f2bf(v);
    }
  }
}

// Batched x-conv GEMM: M = Bn*Tc*Ln rows, K=320, N=512 -> Sx bf16.
// Block 128Mx128N, 8 waves (4wm x 2wn), wave tile 32Mx64N.
__global__ __launch_bounds__(512) void gemm_x(const float* __restrict__ xs,
                                              const short* __restrict__ Bx,
                                              short* __restrict__ Sx,
                                              int tc0, int Tc) {
  __shared__ short aw[132 * 72];
  const int tid = threadIdx.x;
  const int lch = blockIdx.y & 3;
  const int bt  = blockIdx.y >> 2;
  const int b   = bt / Tc, trel = bt - b * Tc;
  const int t   = tc0 + trel;
  const int l0  = lch * 128;

  for (int i = tid; i < 132 * 16; i += 512) {
    int r = i >> 4, c4 = (i & 15) * 4;
    int l = l0 - 2 + r;
    s16x4 v = {0, 0, 0, 0};
    if (l >= 0 && l < Ln) {
      f32x4 f = *(const f32x4*)&xs[(((size_t)b * Tn + t) * Ln + l) * Cn + c4];
      v[0] = f2bf(f[0]); v[1] = f2bf(f[1]); v[2] = f2bf(f[2]); v[3] = f2bf(f[3]);
    }
    *(s16x4*)&aw[r * 72 + c4] = v;
  }
  __syncthreads();

  const int lane = tid & 63, wave = tid >> 6;
  const int quad = lane >> 4, l16 = lane & 15;
  const int wm = wave & 3, wn = wave >> 2;

  const short* Bp[4];
#pragma unroll
  for (int nf = 0; nf < 4; ++nf)
    Bp[nf] = Bx + (size_t)(blockIdx.x * 8 + wn * 4 + nf) * (KCX * 512) + lane * 8;
  const int ar0 = (wm * 32 + l16) * 72 + quad * 8;

  f32x4 acc[2][4] = {};
  bf16x8 a_c[2], b_c[4];
  a_c[0] = *(const bf16x8*)&aw[ar0];
  a_c[1] = *(const bf16x8*)&aw[ar0 + 16 * 72];
#pragma unroll
  for (int nf = 0; nf < 4; ++nf) b_c[nf] = *(const bf16x8*)(Bp[nf]);

  int kk = 0, jj = 0;
  for (int kc = 0; kc < KCX; ++kc) {
    bool last = (kc == KCX - 1);
    int jj2 = jj + 32, kk2 = kk;
    if (jj2 == 64) { jj2 = 0; kk2 = kk + 1; }
    if (last) { jj2 = jj; kk2 = kk; }
    int kb = last ? kc : kc + 1;
    const short* ar = &aw[ar0 + kk2 * 72 + jj2];
    bf16x8 a_n[2], b_n[4];
    a_n[0] = *(const bf16x8*)(ar);
    a_n[1] = *(const bf16x8*)(ar + 16 * 72);
#pragma unroll
    for (int nf = 0; nf < 4; ++nf) b_n[nf] = *(const bf16x8*)(Bp[nf] + kb * 512);
#pragma unroll
    for (int mi = 0; mi < 2; ++mi)
#pragma unroll
      for (int nf = 0; nf < 4; ++nf)
        acc[mi][nf] = __builtin_amdgcn_mfma_f32_16x16x32_bf16(a_c[mi], b_c[nf], acc[mi][nf], 0, 0, 0);
    a_c[0] = a_n[0]; a_c[1] = a_n[1];
#pragma unroll
    for (int nf = 0; nf < 4; ++nf) b_c[nf] = b_n[nf];
    kk = kk2; jj = jj2;
  }

  const size_t mrow = (size_t)(b * Tc + trel) * Ln + l0 + wm * 32 + quad * 4;
  const int n0 = blockIdx.x * 128 + wn * 64 + l16;
#pragma unroll
  for (int nf = 0; nf < 4; ++nf) {
    int nn = n0 + nf * 16;
    bool ok = (nn < 3 * SW) && ((nn - (nn / SW) * SW) < Hn);
    if (ok)
#pragma unroll
      for (int mi = 0; mi < 2; ++mi)
#pragma unroll
        for (int r = 0; r < 4; ++r)
          Sx[(mrow + mi * 16 + r) * NS + nn] = f2bf(acc[mi][nf][r]);
  }
}

// Recurrent h-conv GEMM: M=8192, K=800, N=512 -> Sh bf16. Grid (4,64) = 256 blocks.
__global__ __launch_bounds__(512) void gemm_h(const short* __restrict__ hbf,
                                              const short* __restrict__ Bh,
                                              short* __restrict__ Sh) {
  __shared__ short aw[132 * 168];   // 44.4 KB window
  const int tid = threadIdx.x;
  const int bb = blockIdx.y >> 2;
  const int l0 = (blockIdx.y & 3) * 128;

  for (int i = tid; i < 132 * 40; i += 512) {
    int r = i / 40, c4 = (i - r * 40) * 4;
    int l = l0 - 2 + r;
    s16x4 v = {0, 0, 0, 0};
    if (l >= 0 && l < Ln) v = *(const s16x4*)&hbf[((size_t)bb * Ln + l) * HP + c4];
    *(s16x4*)&aw[r * 168 + c4] = v;
  }
  __syncthreads();

  const int lane = tid & 63, wave = tid >> 6;
  const int quad = lane >> 4, l16 = lane & 15;
  const int wm = wave & 3, wn = wave >> 2;

  const short* Bp[4];
#pragma unroll
  for (int nf = 0; nf < 4; ++nf)
    Bp[nf] = Bh + (size_t)(blockIdx.x * 8 + wn * 4 + nf) * (KCH * 512) + lane * 8;
  const int ar0 = (wm * 32 + l16) * 168 + quad * 8;

  f32x4 acc[2][4] = {};
  bf16x8 a_c[2], b_c[4];
  a_c[0] = *(const bf16x8*)&aw[ar0];
  a_c[1] = *(const bf16x8*)&aw[ar0 + 16 * 168];
#pragma unroll
  for (int nf = 0; nf < 4; ++nf) b_c[nf] = *(const bf16x8*)(Bp[nf]);

  int kk = 0, jj = 0;
  for (int kc = 0; kc < KCH; ++kc) {
    bool last = (kc == KCH - 1);
    int jj2 = jj + 32, kk2 = kk;
    if (jj2 == 160) { jj2 = 0; kk2 = kk + 1; }
    if (last) { jj2 = jj; kk2 = kk; }
    int kb = last ? kc : kc + 1;
    const short* ar = &aw[ar0 + kk2 * 168 + jj2];
    bf16x8 a_n[2], b_n[4];
    a_n[0] = *(const bf16x8*)(ar);
    a_n[1] = *(const bf16x8*)(ar + 16 * 168);
#pragma unroll
    for (int nf = 0; nf < 4; ++nf) b_n[nf] = *(const bf16x8*)(Bp[nf] + kb * 512);
#pragma unroll
    for (int mi = 0; mi < 2; ++mi)
#pragma unroll
      for (int nf = 0; nf < 4; ++nf)
        acc[mi][nf] = __builtin_amdgcn_mfma_f32_16x16x32_bf16(a_c[mi], b_c[nf], acc[mi][nf], 0, 0, 0);
    a_c[0] = a_n[0]; a_c[1] = a_n[1];
#pragma unroll
    for (int nf = 0; nf < 4; ++nf) b_c[nf] = b_n[nf];
    kk = kk2; jj = jj2;
  }

  const int m0 = blockIdx.y * 128 + wm * 32 + quad * 4;
  const int n0 = blockIdx.x * 128 + wn * 64 + l16;
#pragma unroll
  for (int nf = 0; nf < 4; ++nf) {
    int nn = n0 + nf * 16;
    bool ok = (nn < 3 * SW) && ((nn - (nn / SW) * SW) < Hn);
    if (ok)
#pragma unroll
      for (int mi = 0; mi < 2; ++mi)
#pragma unroll
        for (int r = 0; r < 4; ++r)
          Sh[(size_t)(m0 + mi * 16 + r) * NS + nn] = f2bf(acc[mi][nf][r]);
  }
}

// Pointwise GRU gates. h fp32 carried; bf16 shadow for the next GEMM.
__global__ __launch_bounds__(256) void update_h(const short* __restrict__ Sh,
                                                const short* __restrict__ Sx,
                                                float* __restrict__ hf,
                                                short* __restrict__ hb,
                                                int trel, int Tc) {
  int idx = blockIdx.x * 256 + threadIdx.x;
  if (idx >= Mtot * Hn) return;
  int m = idx / Hn, j = idx - m * Hn;
  int b = m >> 9, l = m & 511;
  const short* sh = Sh + (size_t)m * NS;
  const short* sx = Sx + ((size_t)(b * Tc + trel) * Ln + l) * NS;
  float r = 1.f / (1.f + __expf(-(bf2f(sh[j]) + bf2f(sx[j]))));
  float z = 1.f / (1.f + __expf(-(bf2f(sh[SW + j]) + bf2f(sx[SW + j]))));
  float xg = bf2f(sx[2 * SW + j]) + r * bf2f(sh[2 * SW + j]);
  xg = fminf(fmaxf(xg, -15.f), 15.f);
  float e = __expf(2.f * xg);
  float n = (e - 1.f) / (e + 1.f);
  float hn = (1.f - z) * n + z * hf[idx];
  hf[idx] = hn;
  hb[m * HP + j] = f2bf(hn);
}

// Head: thread-per-output fp32 (coalesced W cols, broadcast h row via L1).
__global__ __launch_bounds__(256) void head1(const float* __restrict__ hf,
                                             const float* __restrict__ W1,
                                             const float* __restrict__ b1,
                                             float* __restrict__ hdn) {
  int idx = blockIdx.x * 256 + threadIdx.x;
  if (idx >= Mtot * Hn) return;
  int m = idx / Hn, j = idx - m * Hn;
  const float* hr = hf + (size_t)m * Hn;
  float acc = b1[j];
#pragma unroll 10
  for (int i = 0; i < Hn; ++i) acc = fmaf(hr[i], W1[i * Hn + j], acc);
  hdn[idx] = acc / (1.f + __expf(-acc));   // silu
}
__global__ __launch_bounds__(256) void head2(const float* __restrict__ hdn,
                                             const float* __restrict__ W2,
                                             const float* __restrict__ b2,
                                             float* __restrict__ out) {
  int idx = blockIdx.x * 256 + threadIdx.x;
  if (idx >= Mtot * 24) return;
  int m = idx / 24, j = idx - m * 24;
  const float* hr = hdn + (size_t)m * Hn;
  float acc = b2[j];
#pragma unroll 10
  for (int i = 0; i < Hn; ++i) acc = fmaf(hr[i], W2[i * 24 + j], acc);
  out[idx] = acc;
}

extern "C" void kernel_launch(void* const* d_in, const int* in_sizes, int n_in,
                              void* d_out, int out_size, void* d_ws, size_t ws_size,
                              hipStream_t stream) {
  const float* xs = (const float*)d_in[0];
  const float* ki = (const float*)d_in[1];
  const float* kh = (const float*)d_in[2];
  const float* W1 = (const float*)d_in[3];
  const float* b1 = (const float*)d_in[4];
  const float* W2 = (const float*)d_in[5];
  const float* b2 = (const float*)d_in[6];
  float* out = (float*)d_out;

  char* p = (char*)d_ws;
  short* Sh = (short*)p; p += (size_t)Mtot * NS * 2;       // 8 MiB
  float* hf = (float*)p; p += (size_t)Mtot * Hn * 4;       // 4.7 MiB
  float* hdn = (float*)p; p += (size_t)Mtot * Hn * 4;      // 4.7 MiB
  short* hb = (short*)p; p += (size_t)Mtot * HP * 2;       // 2.5 MiB
  short* Bh = (short*)p; p += (size_t)32 * KCH * 512 * 2;  // 0.8 MiB
  short* Bx = (short*)p; p += (size_t)32 * KCX * 512 * 2;  // 0.3 MiB
  size_t fixed = (size_t)(p - (char*)d_ws);
  size_t per_t = (size_t)Bn * Ln * NS * 2;                 // 8 MiB per timestep
  int Tc = 1;
  for (int c : {64, 32, 16, 8, 4, 2}) {
    if (fixed + (size_t)c * per_t <= ws_size) { Tc = c; break; }
  }
  short* Sx = (short*)p;

  hipMemsetAsync(hf, 0, (size_t)Mtot * Hn * 4, stream);
  hipMemsetAsync(hb, 0, (size_t)Mtot * HP * 2, stream);  // pad cols stay zero
  pack_weights<<<(32 * (KCH + KCX) * 512 + 255) / 256, 256, 0, stream>>>(ki, kh, Bx, Bh);

  for (int tc0 = 0; tc0 < Tn; tc0 += Tc) {
    gemm_x<<<dim3(4, Bn * Tc * 4), 512, 0, stream>>>(xs, Bx, Sx, tc0, Tc);
    for (int t = tc0; t < tc0 + Tc; ++t) {
      gemm_h<<<dim3(4, 64), 512, 0, stream>>>(hb, Bh, Sh);
      update_h<<<(Mtot * Hn + 255) / 256, 256, 0, stream>>>(Sh, Sx, hf, hb, t - tc0, Tc);
    }
  }
  head1<<<(Mtot * Hn + 255) / 256, 256, 0, stream>>>(hf, W1, b1, hdn);
  head2<<<(Mtot * 24 + 255) / 256, 256, 0, stream>>>(hdn, W2, b2, out);
}

// Round 4
// 1710.716 us; speedup vs baseline: 1.8943x; 1.2315x over previous
//
#include <hip/hip_runtime.h>

// GlobalNet conv-GRU on MI355X — round 4.
// vs r3: gemm_h + update_h fused into one per-step kernel (gru_step).
// Block = 32 m-rows x full N(480): 10 waves, wave w owns n-tiles {w,w+10,w+20}
// = r/z/n segments for j in [16w,16w+16) -> gates computed in-wave, Sh never
// hits memory. hb double-buffered across launches (read t-1 / write t race).

#define Bn   16
#define Tn   64
#define Ln   512
#define Cn   64
#define Hn   150
#define G3   450
#define NS   512    // Sx width: segments r|z|n at 160 offsets + 32 dead cols
#define SW   160
#define HP   160    // padded hidden
#define KCH  25     // k-chunks (32) for h GEMM (K=800)
#define KCX  10     // k-chunks for x GEMM (K=320)
#define Mtot 8192   // Bn*Ln

typedef __bf16 bf16x8 __attribute__((ext_vector_type(8)));
typedef float  f32x4  __attribute__((ext_vector_type(4)));
typedef short  s16x4  __attribute__((ext_vector_type(4)));

__device__ inline short f2bf(float f) {
  unsigned u = __builtin_bit_cast(unsigned, f);
  u += 0x7fffu + ((u >> 16) & 1u);   // RNE (finite inputs)
  return (short)(u >> 16);
}
__device__ inline float bf2f(short s) {
  unsigned u = ((unsigned)(unsigned short)s) << 16;
  return __builtin_bit_cast(float, u);
}

// Packed B layout: [nt (n/16)][kc][lane (quad*16+l16)][j (8)] shorts.
// Fragment element: B[k = kc*32+quad*8+j][n = nt*16+l16].
// n maps (seg=n/160, jl=n%160) -> orig col seg*150+jl (zero pad elsewhere).
__global__ __launch_bounds__(256) void pack_weights(const float* __restrict__ ki,
                                                    const float* __restrict__ kh,
                                                    short* __restrict__ Bx,
                                                    short* __restrict__ Bh) {
  int idx = blockIdx.x * 256 + threadIdx.x;
  if (idx < 32 * KCH * 512) {
    int j = idx & 7, lane = (idx >> 3) & 63;
    int rest = idx >> 9;
    int kc = rest % KCH, nt = rest / KCH;
    int quad = lane >> 4, l16 = lane & 15;
    int n = nt * 16 + l16, seg = n / SW, jl = n - seg * SW;
    int kk = kc / 5, jj = (kc - kk * 5) * 32 + quad * 8 + j;
    float v = (seg < 3 && jl < Hn && jj < Hn) ? kh[(kk * Hn + jj) * G3 + seg * Hn + jl] : 0.f;
    Bh[idx] = f2bf(v);
  } else {
    int r = idx - 32 * KCH * 512;
    if (r < 32 * KCX * 512) {
      int j = r & 7, lane = (r >> 3) & 63;
      int rest = r >> 9;
      int kc = rest % KCX, nt = rest / KCX;
      int quad = lane >> 4, l16 = lane & 15;
      int n = nt * 16 + l16, seg = n / SW, jl = n - seg * SW;
      int kk = kc / 2, cc = (kc - kk * 2) * 32 + quad * 8 + j;
      float v = (seg < 3 && jl < Hn) ? ki[(kk * Cn + cc) * G3 + seg * Hn + jl] : 0.f;
      Bx[r] = f2bf(v);
    }
  }
}

// Batched x-conv GEMM (unchanged from r3): M = Bn*Tc*Ln, K=320, N=512 -> Sx bf16.
__global__ __launch_bounds__(512) void gemm_x(const float* __restrict__ xs,
                                              const short* __restrict__ Bx,
                                              short* __restrict__ Sx,
                                              int tc0, int Tc) {
  __shared__ short aw[132 * 72];
  const int tid = threadIdx.x;
  const int lch = blockIdx.y & 3;
  const int bt  = blockIdx.y >> 2;
  const int b   = bt / Tc, trel = bt - b * Tc;
  const int t   = tc0 + trel;
  const int l0  = lch * 128;

  for (int i = tid; i < 132 * 16; i += 512) {
    int r = i >> 4, c4 = (i & 15) * 4;
    int l = l0 - 2 + r;
    s16x4 v = {0, 0, 0, 0};
    if (l >= 0 && l < Ln) {
      f32x4 f = *(const f32x4*)&xs[(((size_t)b * Tn + t) * Ln + l) * Cn + c4];
      v[0] = f2bf(f[0]); v[1] = f2bf(f[1]); v[2] = f2bf(f[2]); v[3] = f2bf(f[3]);
    }
    *(s16x4*)&aw[r * 72 + c4] = v;
  }
  __syncthreads();

  const int lane = tid & 63, wave = tid >> 6;
  const int quad = lane >> 4, l16 = lane & 15;
  const int wm = wave & 3, wn = wave >> 2;

  const short* Bp[4];
#pragma unroll
  for (int nf = 0; nf < 4; ++nf)
    Bp[nf] = Bx + (size_t)(blockIdx.x * 8 + wn * 4 + nf) * (KCX * 512) + lane * 8;
  const int ar0 = (wm * 32 + l16) * 72 + quad * 8;

  f32x4 acc[2][4] = {};
  bf16x8 a_c[2], b_c[4];
  a_c[0] = *(const bf16x8*)&aw[ar0];
  a_c[1] = *(const bf16x8*)&aw[ar0 + 16 * 72];
#pragma unroll
  for (int nf = 0; nf < 4; ++nf) b_c[nf] = *(const bf16x8*)(Bp[nf]);

  int kk = 0, jj = 0;
  for (int kc = 0; kc < KCX; ++kc) {
    bool last = (kc == KCX - 1);
    int jj2 = jj + 32, kk2 = kk;
    if (jj2 == 64) { jj2 = 0; kk2 = kk + 1; }
    if (last) { jj2 = jj; kk2 = kk; }
    int kb = last ? kc : kc + 1;
    const short* ar = &aw[ar0 + kk2 * 72 + jj2];
    bf16x8 a_n[2], b_n[4];
    a_n[0] = *(const bf16x8*)(ar);
    a_n[1] = *(const bf16x8*)(ar + 16 * 72);
#pragma unroll
    for (int nf = 0; nf < 4; ++nf) b_n[nf] = *(const bf16x8*)(Bp[nf] + kb * 512);
#pragma unroll
    for (int mi = 0; mi < 2; ++mi)
#pragma unroll
      for (int nf = 0; nf < 4; ++nf)
        acc[mi][nf] = __builtin_amdgcn_mfma_f32_16x16x32_bf16(a_c[mi], b_c[nf], acc[mi][nf], 0, 0, 0);
    a_c[0] = a_n[0]; a_c[1] = a_n[1];
#pragma unroll
    for (int nf = 0; nf < 4; ++nf) b_c[nf] = b_n[nf];
    kk = kk2; jj = jj2;
  }

  const size_t mrow = (size_t)(b * Tc + trel) * Ln + l0 + wm * 32 + quad * 4;
  const int n0 = blockIdx.x * 128 + wn * 64 + l16;
#pragma unroll
  for (int nf = 0; nf < 4; ++nf) {
    int nn = n0 + nf * 16;
    bool ok = (nn < 3 * SW) && ((nn - (nn / SW) * SW) < Hn);
    if (ok)
#pragma unroll
      for (int mi = 0; mi < 2; ++mi)
#pragma unroll
        for (int r = 0; r < 4; ++r)
          Sx[(mrow + mi * 16 + r) * NS + nn] = f2bf(acc[mi][nf][r]);
  }
}

// Fused recurrent step: h-conv GEMM (32m x 480n x 800k) + GRU gates + h update.
// Grid 256 blocks x 640 threads. Wave w owns n-tiles {w, w+10, w+20}.
__global__ __launch_bounds__(640, 1)
void gru_step(const short* __restrict__ hbin, short* __restrict__ hbout,
              float* __restrict__ hf, const short* __restrict__ Bh,
              const short* __restrict__ Sx, int trel, int Tc) {
  __shared__ short aw[36 * 168];   // 12.1 KB window: rows l0-2 .. l0+33
  const int tid = threadIdx.x;
  const int bb  = blockIdx.x >> 4;
  const int l0  = (blockIdx.x & 15) * 32;

  for (int i = tid; i < 36 * 40; i += 640) {
    int r = i / 40, c4 = (i - r * 40) * 4;
    int l = l0 - 2 + r;
    s16x4 v = {0, 0, 0, 0};
    if (l >= 0 && l < Ln) v = *(const s16x4*)&hbin[((size_t)bb * Ln + l) * HP + c4];
    *(s16x4*)&aw[r * 168 + c4] = v;
  }
  __syncthreads();

  const int lane = tid & 63, w = tid >> 6;
  const int quad = lane >> 4, l16 = lane & 15;

  const short* Bp[3];
  Bp[0] = Bh + (size_t)(w)      * (KCH * 512) + lane * 8;
  Bp[1] = Bh + (size_t)(w + 10) * (KCH * 512) + lane * 8;
  Bp[2] = Bh + (size_t)(w + 20) * (KCH * 512) + lane * 8;
  const int ar0 = l16 * 168 + quad * 8;

  f32x4 acc[2][3] = {};
  bf16x8 bbuf[3][3];   // rolling 3-stage B prefetch [kc%3][seg]
#pragma unroll
  for (int s = 0; s < 2; ++s)
#pragma unroll
    for (int g = 0; g < 3; ++g)
      bbuf[s][g] = *(const bf16x8*)(Bp[g] + s * 512);

#pragma unroll
  for (int kc = 0; kc < KCH; ++kc) {
    const int cur = kc % 3;
    if (kc + 2 < KCH) {
      const int nxt = (kc + 2) % 3;
#pragma unroll
      for (int g = 0; g < 3; ++g)
        bbuf[nxt][g] = *(const bf16x8*)(Bp[g] + (kc + 2) * 512);
    }
    const int kk = kc / 5, jj = (kc - kk * 5) * 32;
    const short* ar = &aw[ar0 + kk * 168 + jj];
    bf16x8 a0 = *(const bf16x8*)(ar);
    bf16x8 a1 = *(const bf16x8*)(ar + 16 * 168);
#pragma unroll
    for (int g = 0; g < 3; ++g) {
      acc[0][g] = __builtin_amdgcn_mfma_f32_16x16x32_bf16(a0, bbuf[cur][g], acc[0][g], 0, 0, 0);
      acc[1][g] = __builtin_amdgcn_mfma_f32_16x16x32_bf16(a1, bbuf[cur][g], acc[1][g], 0, 0, 0);
    }
  }

  // Gates: lane covers j = w*16 + l16, m-rows mi*16 + quad*4 + r.
  const int j = w * 16 + l16;
  if (j < Hn) {
#pragma unroll
    for (int mi = 0; mi < 2; ++mi)
#pragma unroll
      for (int r = 0; r < 4; ++r) {
        const int ml = mi * 16 + quad * 4 + r;
        const size_t mrow = (size_t)bb * Ln + l0 + ml;
        const size_t srow = ((size_t)(bb * Tc + trel) * Ln + l0 + ml) * NS;
        float rg = 1.f / (1.f + __expf(-(bf2f(Sx[srow + j]) + acc[mi][0][r])));
        float zg = 1.f / (1.f + __expf(-(bf2f(Sx[srow + SW + j]) + acc[mi][1][r])));
        float xg = bf2f(Sx[srow + 2 * SW + j]) + rg * acc[mi][2][r];
        xg = fminf(fmaxf(xg, -15.f), 15.f);
        float e = __expf(2.f * xg);
        float n = (e - 1.f) / (e + 1.f);
        float hn = (1.f - zg) * n + zg * hf[mrow * Hn + j];
        hf[mrow * Hn + j] = hn;
        hbout[mrow * HP + j] = f2bf(hn);
      }
  }
}

// Head: thread-per-output fp32.
__global__ __launch_bounds__(256) void head1(const float* __restrict__ hf,
                                             const float* __restrict__ W1,
                                             const float* __restrict__ b1,
                                             float* __restrict__ hdn) {
  int idx = blockIdx.x * 256 + threadIdx.x;
  if (idx >= Mtot * Hn) return;
  int m = idx / Hn, j = idx - m * Hn;
  const float* hr = hf + (size_t)m * Hn;
  float acc = b1[j];
#pragma unroll 10
  for (int i = 0; i < Hn; ++i) acc = fmaf(hr[i], W1[i * Hn + j], acc);
  hdn[idx] = acc / (1.f + __expf(-acc));   // silu
}
__global__ __launch_bounds__(256) void head2(const float* __restrict__ hdn,
                                             const float* __restrict__ W2,
                                             const float* __restrict__ b2,
                                             float* __restrict__ out) {
  int idx = blockIdx.x * 256 + threadIdx.x;
  if (idx >= Mtot * 24) return;
  int m = idx / 24, j = idx - m * 24;
  const float* hr = hdn + (size_t)m * Hn;
  float acc = b2[j];
#pragma unroll 10
  for (int i = 0; i < Hn; ++i) acc = fmaf(hr[i], W2[i * 24 + j], acc);
  out[idx] = acc;
}

extern "C" void kernel_launch(void* const* d_in, const int* in_sizes, int n_in,
                              void* d_out, int out_size, void* d_ws, size_t ws_size,
                              hipStream_t stream) {
  const float* xs = (const float*)d_in[0];
  const float* ki = (const float*)d_in[1];
  const float* kh = (const float*)d_in[2];
  const float* W1 = (const float*)d_in[3];
  const float* b1 = (const float*)d_in[4];
  const float* W2 = (const float*)d_in[5];
  const float* b2 = (const float*)d_in[6];
  float* out = (float*)d_out;

  char* p = (char*)d_ws;
  float* hf  = (float*)p; p += (size_t)Mtot * Hn * 4;       // 4.7 MiB
  float* hdn = (float*)p; p += (size_t)Mtot * Hn * 4;       // 4.7 MiB
  short* hbA = (short*)p; p += (size_t)Mtot * HP * 2;       // 2.5 MiB
  short* hbB = (short*)p; p += (size_t)Mtot * HP * 2;       // 2.5 MiB
  short* Bh  = (short*)p; p += (size_t)32 * KCH * 512 * 2;  // 0.8 MiB
  short* Bx  = (short*)p; p += (size_t)32 * KCX * 512 * 2;  // 0.3 MiB
  size_t fixed = (size_t)(p - (char*)d_ws);
  size_t per_t = (size_t)Bn * Ln * NS * 2;                  // 8 MiB per timestep
  int Tc = 1;
  for (int c : {64, 32, 16, 8, 4, 2}) {
    if (fixed + (size_t)c * per_t <= ws_size) { Tc = c; break; }
  }
  short* Sx = (short*)p;

  hipMemsetAsync(hf, 0, (size_t)Mtot * Hn * 4, stream);
  hipMemsetAsync(hbA, 0, (size_t)Mtot * HP * 2 * 2, stream);  // both buffers; pads stay 0
  pack_weights<<<(32 * (KCH + KCX) * 512 + 255) / 256, 256, 0, stream>>>(ki, kh, Bx, Bh);

  for (int tc0 = 0; tc0 < Tn; tc0 += Tc) {
    gemm_x<<<dim3(4, Bn * Tc * 4), 512, 0, stream>>>(xs, Bx, Sx, tc0, Tc);
    for (int t = tc0; t < tc0 + Tc; ++t) {
      short* hin  = (t & 1) ? hbB : hbA;
      short* hout = (t & 1) ? hbA : hbB;
      gru_step<<<256, 640, 0, stream>>>(hin, hout, hf, Bh, Sx, t - tc0, Tc);
    }
  }
  head1<<<(Mtot * Hn + 255) / 256, 256, 0, stream>>>(hf, W1, b1, hdn);
  head2<<<(Mtot * 24 + 255) / 256, 256, 0, stream>>>(hdn, W2, b2, out);
}

// Round 5
// 1295.988 us; speedup vs baseline: 2.5005x; 1.3200x over previous
//
#include <hip/hip_runtime.h>

// GlobalNet conv-GRU on MI355X — round 5.
// vs r4: x-conv fused INTO gru_step (r/z gates: extend K with Bx chunks into the
// same accumulators; n gate: separate axn accumulator since iin and hin combine
// non-additively). Deletes gemm_x dispatch (211 us), Sx write (245 MB) and Sx
// read (~503 MB over the scan). Deeper B prefetch (4-stage h, 3-stage x, x primed
// before h-loop) for L2 latency hiding at 2.5 waves/SIMD.

#define Bn   16
#define Tn   64
#define Ln   512
#define Cn   64
#define Hn   150
#define G3   450
#define SW   160
#define HP   160    // padded hidden
#define KCH  25     // k-chunks (32) for h GEMM (K=800)
#define KCX  10     // k-chunks for x GEMM (K=320)
#define Mtot 8192   // Bn*Ln

typedef __bf16 bf16x8 __attribute__((ext_vector_type(8)));
typedef float  f32x4  __attribute__((ext_vector_type(4)));
typedef short  s16x4  __attribute__((ext_vector_type(4)));

__device__ inline short f2bf(float f) {
  unsigned u = __builtin_bit_cast(unsigned, f);
  u += 0x7fffu + ((u >> 16) & 1u);   // RNE (finite inputs)
  return (short)(u >> 16);
}

// Packed B layout: [nt (n/16)][kc][lane (quad*16+l16)][j (8)] shorts.
// Fragment element: B[k = kc*32+quad*8+j][n = nt*16+l16].
// n maps (seg=n/160, jl=n%160) -> orig col seg*150+jl (zero pad elsewhere).
__global__ __launch_bounds__(256) void pack_weights(const float* __restrict__ ki,
                                                    const float* __restrict__ kh,
                                                    short* __restrict__ Bx,
                                                    short* __restrict__ Bh) {
  int idx = blockIdx.x * 256 + threadIdx.x;
  if (idx < 32 * KCH * 512) {
    int j = idx & 7, lane = (idx >> 3) & 63;
    int rest = idx >> 9;
    int kc = rest % KCH, nt = rest / KCH;
    int quad = lane >> 4, l16 = lane & 15;
    int n = nt * 16 + l16, seg = n / SW, jl = n - seg * SW;
    int kk = kc / 5, jj = (kc - kk * 5) * 32 + quad * 8 + j;
    float v = (seg < 3 && jl < Hn && jj < Hn) ? kh[(kk * Hn + jj) * G3 + seg * Hn + jl] : 0.f;
    Bh[idx] = f2bf(v);
  } else {
    int r = idx - 32 * KCH * 512;
    if (r < 32 * KCX * 512) {
      int j = r & 7, lane = (r >> 3) & 63;
      int rest = r >> 9;
      int kc = rest % KCX, nt = rest / KCX;
      int quad = lane >> 4, l16 = lane & 15;
      int n = nt * 16 + l16, seg = n / SW, jl = n - seg * SW;
      int kk = kc / 2, cc = (kc - kk * 2) * 32 + quad * 8 + j;
      float v = (seg < 3 && jl < Hn) ? ki[(kk * Cn + cc) * G3 + seg * Hn + jl] : 0.f;
      Bx[r] = f2bf(v);
    }
  }
}

// Fully-fused recurrent step: h-conv (K=800) + x-conv (K=320) + gates + h update.
// Grid 256 blocks x 640 threads (10 waves). Block = 32 m-rows x full N(480).
// Wave w owns n-tiles {w, w+10, w+20} = r/z/n segments for j in [16w,16w+16).
__global__ __launch_bounds__(640)
void gru_step(const short* __restrict__ hbin, short* __restrict__ hbout,
              float* __restrict__ hf, const short* __restrict__ Bh,
              const short* __restrict__ Bx, const float* __restrict__ xs, int t) {
  __shared__ short awh[36 * 168];   // h window rows l0-2..l0+33, 160 ch (12.1 KB)
  __shared__ short awx[36 * 72];    // x window, 64 ch (5.2 KB)
  const int tid = threadIdx.x;
  const int bb  = blockIdx.x >> 4;
  const int l0  = (blockIdx.x & 15) * 32;

  for (int i = tid; i < 36 * 40; i += 640) {
    int r = i / 40, c4 = (i - r * 40) * 4;
    int l = l0 - 2 + r;
    s16x4 v = {0, 0, 0, 0};
    if (l >= 0 && l < Ln) v = *(const s16x4*)&hbin[((size_t)bb * Ln + l) * HP + c4];
    *(s16x4*)&awh[r * 168 + c4] = v;
  }
  for (int i = tid; i < 36 * 16; i += 640) {
    int r = i >> 4, c4 = (i & 15) * 4;
    int l = l0 - 2 + r;
    s16x4 v = {0, 0, 0, 0};
    if (l >= 0 && l < Ln) {
      f32x4 f = *(const f32x4*)&xs[(((size_t)bb * Tn + t) * Ln + l) * Cn + c4];
      v[0] = f2bf(f[0]); v[1] = f2bf(f[1]); v[2] = f2bf(f[2]); v[3] = f2bf(f[3]);
    }
    *(s16x4*)&awx[r * 72 + c4] = v;
  }
  __syncthreads();

  const int lane = tid & 63, w = tid >> 6;
  const int quad = lane >> 4, l16 = lane & 15;

  const short* Bph[3];
  const short* Bpx[3];
#pragma unroll
  for (int g = 0; g < 3; ++g) {
    Bph[g] = Bh + (size_t)(w + 10 * g) * (KCH * 512) + lane * 8;
    Bpx[g] = Bx + (size_t)(w + 10 * g) * (KCX * 512) + lane * 8;
  }
  const int arh = l16 * 168 + quad * 8;
  const int arx = l16 * 72 + quad * 8;

  f32x4 acc[2][3] = {};   // r | z | n(h-part)
  f32x4 axn[2] = {};      // n(x-part), kept separate: n = tanh(iin + r*hin)

  // Prime x-phase B loads early (independent of the h loop — deep in flight).
  bf16x8 bx[3][3];
#pragma unroll
  for (int s = 0; s < 2; ++s)
#pragma unroll
    for (int g = 0; g < 3; ++g) bx[s][g] = *(const bf16x8*)(Bpx[g] + s * 512);

  bf16x8 bh[4][3];   // 4-stage rolling prefetch
#pragma unroll
  for (int s = 0; s < 3; ++s)
#pragma unroll
    for (int g = 0; g < 3; ++g) bh[s][g] = *(const bf16x8*)(Bph[g] + s * 512);

#pragma unroll
  for (int kc = 0; kc < KCH; ++kc) {
    const int cur = kc & 3;
    if (kc + 3 < KCH) {
      const int nxt = (kc + 3) & 3;
#pragma unroll
      for (int g = 0; g < 3; ++g)
        bh[nxt][g] = *(const bf16x8*)(Bph[g] + (kc + 3) * 512);
    }
    const int kk = kc / 5, jj = (kc - kk * 5) * 32;
    const short* ar = &awh[arh + kk * 168 + jj];
    bf16x8 a0 = *(const bf16x8*)(ar);
    bf16x8 a1 = *(const bf16x8*)(ar + 16 * 168);
#pragma unroll
    for (int g = 0; g < 3; ++g) {
      acc[0][g] = __builtin_amdgcn_mfma_f32_16x16x32_bf16(a0, bh[cur][g], acc[0][g], 0, 0, 0);
      acc[1][g] = __builtin_amdgcn_mfma_f32_16x16x32_bf16(a1, bh[cur][g], acc[1][g], 0, 0, 0);
    }
  }

#pragma unroll
  for (int kc = 0; kc < KCX; ++kc) {
    const int cur = kc % 3;
    if (kc + 2 < KCX) {
      const int nxt = (kc + 2) % 3;
#pragma unroll
      for (int g = 0; g < 3; ++g)
        bx[nxt][g] = *(const bf16x8*)(Bpx[g] + (kc + 2) * 512);
    }
    const int kk = kc >> 1, jj = (kc & 1) * 32;
    const short* ar = &awx[arx + kk * 72 + jj];
    bf16x8 a0 = *(const bf16x8*)(ar);
    bf16x8 a1 = *(const bf16x8*)(ar + 16 * 72);
    acc[0][0] = __builtin_amdgcn_mfma_f32_16x16x32_bf16(a0, bx[cur][0], acc[0][0], 0, 0, 0);
    acc[1][0] = __builtin_amdgcn_mfma_f32_16x16x32_bf16(a1, bx[cur][0], acc[1][0], 0, 0, 0);
    acc[0][1] = __builtin_amdgcn_mfma_f32_16x16x32_bf16(a0, bx[cur][1], acc[0][1], 0, 0, 0);
    acc[1][1] = __builtin_amdgcn_mfma_f32_16x16x32_bf16(a1, bx[cur][1], acc[1][1], 0, 0, 0);
    axn[0]    = __builtin_amdgcn_mfma_f32_16x16x32_bf16(a0, bx[cur][2], axn[0], 0, 0, 0);
    axn[1]    = __builtin_amdgcn_mfma_f32_16x16x32_bf16(a1, bx[cur][2], axn[1], 0, 0, 0);
  }

  // Gates: lane covers j = w*16 + l16, m-rows mi*16 + quad*4 + r.
  const int j = w * 16 + l16;
  if (j < Hn) {
#pragma unroll
    for (int mi = 0; mi < 2; ++mi)
#pragma unroll
      for (int r = 0; r < 4; ++r) {
        const int ml = mi * 16 + quad * 4 + r;
        const size_t mrow = (size_t)bb * Ln + l0 + ml;
        float rg = 1.f / (1.f + __expf(-acc[mi][0][r]));
        float zg = 1.f / (1.f + __expf(-acc[mi][1][r]));
        float xg = axn[mi][r] + rg * acc[mi][2][r];
        xg = fminf(fmaxf(xg, -15.f), 15.f);
        float e = __expf(2.f * xg);
        float n = (e - 1.f) / (e + 1.f);
        float hn = (1.f - zg) * n + zg * hf[mrow * Hn + j];
        hf[mrow * Hn + j] = hn;
        hbout[mrow * HP + j] = f2bf(hn);
      }
  }
}

// Head: thread-per-output fp32.
__global__ __launch_bounds__(256) void head1(const float* __restrict__ hf,
                                             const float* __restrict__ W1,
                                             const float* __restrict__ b1,
                                             float* __restrict__ hdn) {
  int idx = blockIdx.x * 256 + threadIdx.x;
  if (idx >= Mtot * Hn) return;
  int m = idx / Hn, j = idx - m * Hn;
  const float* hr = hf + (size_t)m * Hn;
  float acc = b1[j];
#pragma unroll 10
  for (int i = 0; i < Hn; ++i) acc = fmaf(hr[i], W1[i * Hn + j], acc);
  hdn[idx] = acc / (1.f + __expf(-acc));   // silu
}
__global__ __launch_bounds__(256) void head2(const float* __restrict__ hdn,
                                             const float* __restrict__ W2,
                                             const float* __restrict__ b2,
                                             float* __restrict__ out) {
  int idx = blockIdx.x * 256 + threadIdx.x;
  if (idx >= Mtot * 24) return;
  int m = idx / 24, j = idx - m * 24;
  const float* hr = hdn + (size_t)m * Hn;
  float acc = b2[j];
#pragma unroll 10
  for (int i = 0; i < Hn; ++i) acc = fmaf(hr[i], W2[i * 24 + j], acc);
  out[idx] = acc;
}

extern "C" void kernel_launch(void* const* d_in, const int* in_sizes, int n_in,
                              void* d_out, int out_size, void* d_ws, size_t ws_size,
                              hipStream_t stream) {
  const float* xs = (const float*)d_in[0];
  const float* ki = (const float*)d_in[1];
  const float* kh = (const float*)d_in[2];
  const float* W1 = (const float*)d_in[3];
  const float* b1 = (const float*)d_in[4];
  const float* W2 = (const float*)d_in[5];
  const float* b2 = (const float*)d_in[6];
  float* out = (float*)d_out;

  char* p = (char*)d_ws;
  float* hf  = (float*)p; p += (size_t)Mtot * Hn * 4;       // 4.7 MiB
  float* hdn = (float*)p; p += (size_t)Mtot * Hn * 4;       // 4.7 MiB
  short* hbA = (short*)p; p += (size_t)Mtot * HP * 2;       // 2.5 MiB
  short* hbB = (short*)p; p += (size_t)Mtot * HP * 2;       // 2.5 MiB
  short* Bh  = (short*)p; p += (size_t)32 * KCH * 512 * 2;  // 0.8 MiB
  short* Bx  = (short*)p; p += (size_t)32 * KCX * 512 * 2;  // 0.3 MiB

  hipMemsetAsync(hf, 0, (size_t)Mtot * Hn * 4, stream);
  hipMemsetAsync(hbA, 0, (size_t)Mtot * HP * 2 * 2, stream);  // both buffers; pads stay 0
  pack_weights<<<(32 * (KCH + KCX) * 512 + 255) / 256, 256, 0, stream>>>(ki, kh, Bx, Bh);

  for (int t = 0; t < Tn; ++t) {
    short* hin  = (t & 1) ? hbB : hbA;
    short* hout = (t & 1) ? hbA : hbB;
    gru_step<<<256, 640, 0, stream>>>(hin, hout, hf, Bh, Bx, xs, t);
  }
  head1<<<(Mtot * Hn + 255) / 256, 256, 0, stream>>>(hf, W1, b1, hdn);
  head2<<<(Mtot * 24 + 255) / 256, 256, 0, stream>>>(hdn, W2, b2, out);
}